// Round 6
// baseline (25.172 us; speedup 1.0000x reference)
//
#include <hip/hip_runtime.h>
#include <math.h>

// MAM fully-connected: out[r][o] = max_k(x[r][k]*W[o][k]) + min_k(x[r][k]*W[o][k]) + b[o]
// x: (1024, 512) f32, W: (512, 512) f32, b: (512,), out: (1024, 512) f32.
//
// v6: DS-pipe decongestion. R3/R5 were LDS-bound (every wave re-read every W
// granule per 2 rows + x broadcasts: ~25-30K DS cyc/CU). Fix:
//  - W chunk (64 outs x 64 k) -> 64 VGPRs per wave ONCE per chunk
//    (16x ds_read_b128, XOR-swizzled, 8 words/bank), reused across RPW=4 rows
//    -> W ds_reads cut 8x (9.4K cyc/CU)
//  - x: NO LDS. Addresses fully wave-uniform (-> s_load scalarization; worst
//    case 1-line uniform VMEM) -> zero DS cycles
//  - W staged global->LDS coalesced via global_load_lds w16, source
//    pre-swizzled, linear LDS dest; double-buffered, 1 barrier/chunk
//  - inner: per (r,j): 4 v_mul + 2 v_max3 + 2 v_min3 on held registers
//    -> VALU-bound at ~6.8us/CU issue floor (DS now at ~4.9us)

#define O_TOTAL 512
#define K_TOTAL 512
#define OBLK 64
#define NWAVE 4
#define RPW 4                    // rows per wave
#define RPB (NWAVE * RPW)        // 16 rows per block
#define KCH 64                   // K chunk
#define NCHUNK (K_TOTAL / KCH)   // 8
#define NJ (KCH / 4)             // 16 granules per chunk

__device__ __forceinline__ void stage16(const float* g, float* lds_base) {
#if __has_builtin(__builtin_amdgcn_global_load_lds)
  __builtin_amdgcn_global_load_lds(
      (__attribute__((address_space(1))) unsigned int*)g,
      (__attribute__((address_space(3))) unsigned int*)lds_base, 16, 0, 0);
#else
  *reinterpret_cast<float4*>(lds_base + (threadIdx.x & 63) * 4) =
      *reinterpret_cast<const float4*>(g);
#endif
}

__global__ __launch_bounds__(256, 2)
void mam_fc_kernel(const float* __restrict__ x, const float* __restrict__ W,
                   const float* __restrict__ bias, float* __restrict__ out) {
  __shared__ __align__(16) float Wl[2][OBLK * KCH];   // 2 x 16 KB

  const int t = threadIdx.x;
  const int lane = t & 63;
  const int wv = __builtin_amdgcn_readfirstlane(t >> 6);
  const int ob = blockIdx.x & 7;        // 8 out-blocks of 64
  const int rg = blockIdx.x >> 3;       // 64 row-groups of 16
  const int o0 = ob * OBLK;
  const int rowBase = rg * RPB + wv * RPW;   // this wave's first row (uniform)

  // W staging: wave wv, pass p -> row orow = wv*16+p*4+(lane>>4); phys granule
  // lane&15 holds logical granule (lane&15)^(orow&15) (pre-swizzled source,
  // linear LDS dest as global_load_lds requires)
  const float* srcW[4];
  int dstWoff[4];
#pragma unroll
  for (int p = 0; p < 4; ++p) {
    const int orow = wv * 16 + p * 4 + (lane >> 4);
    const int g = (lane & 15) ^ (orow & 15);
    srcW[p] = W + (size_t)(o0 + orow) * K_TOTAL + g * 4;
    dstWoff[p] = (wv * 16 + p * 4) * KCH;   // wave-uniform
  }

  const float* xr = x + (size_t)rowBase * K_TOTAL;   // wave-uniform pointer

  float amax[RPW], amin[RPW];
#pragma unroll
  for (int r = 0; r < RPW; ++r) { amax[r] = -INFINITY; amin[r] = INFINITY; }

  // in-loop W read: row=lane, phys granule j^(lane&15); XOR fields disjoint
  const unsigned baseW = (unsigned)(lane * (KCH * 4) + (lane & 15) * 16);

  // prologue: stage chunk 0 into buf 0
#pragma unroll
  for (int p = 0; p < 4; ++p) stage16(srcW[p], &Wl[0][dstWoff[p]]);

#pragma unroll 1
  for (int c = 0; c < NCHUNK; ++c) {
    __syncthreads();   // buf[c&1] staged (compiler drains vmcnt before barrier)

    if (c + 1 < NCHUNK) {   // issue next-chunk staging; drained at NEXT barrier
      const int kOff = (c + 1) * KCH;
#pragma unroll
      for (int p = 0; p < 4; ++p)
        stage16(srcW[p] + kOff, &Wl[(c + 1) & 1][dstWoff[p]]);
    }

    // W chunk -> 64 VGPRs (16 b128 reads, bank-optimal), reused by all rows
    const char* wb = (const char*)&Wl[c & 1][0];
    float4 w[NJ];
#pragma unroll
    for (int j = 0; j < NJ; ++j)
      w[j] = *reinterpret_cast<const float4*>(wb + (baseW ^ (unsigned)(j * 16)));

#pragma unroll
    for (int r = 0; r < RPW; ++r) {
      const float* xrc = xr + (size_t)r * K_TOTAL + c * KCH;  // uniform
#pragma unroll
      for (int j = 0; j < NJ; ++j) {
        const float4 xv = *reinterpret_cast<const float4*>(xrc + j * 4);
        const float p0 = xv.x * w[j].x;
        const float p1 = xv.y * w[j].y;
        const float p2 = xv.z * w[j].z;
        const float p3 = xv.w * w[j].w;
        // 4-deep chains -> 2x v_max3 / 2x v_min3
        amax[r] = fmaxf(fmaxf(fmaxf(fmaxf(amax[r], p0), p1), p2), p3);
        amin[r] = fminf(fminf(fminf(fminf(amin[r], p0), p1), p2), p3);
      }
    }
  }

  const float bv = bias[o0 + lane];
#pragma unroll
  for (int r = 0; r < RPW; ++r) {
    out[(size_t)(rowBase + r) * O_TOTAL + o0 + lane] =
        amax[r] + amin[r] + bv;   // lanes -> consecutive: coalesced
  }
}

extern "C" void kernel_launch(void* const* d_in, const int* in_sizes, int n_in,
                              void* d_out, int out_size, void* d_ws, size_t ws_size,
                              hipStream_t stream) {
  const float* x = (const float*)d_in[0];    // (1024, 512)
  const float* W = (const float*)d_in[1];    // (512, 512)
  const float* b = (const float*)d_in[2];    // (512,)
  float* out = (float*)d_out;                // (1024, 512)

  const int nrows = in_sizes[0] / K_TOTAL;                 // 1024
  const int nblocks = (O_TOTAL / OBLK) * (nrows / RPB);    // 8 * 64 = 512
  mam_fc_kernel<<<dim3(nblocks), dim3(256), 0, stream>>>(x, W, b, out);
}

// Round 7
// 21.241 us; speedup vs baseline: 1.1850x; 1.1850x over previous
//
#include <hip/hip_runtime.h>
#include <math.h>

// MAM fully-connected: out[r][o] = max_k(x[r][k]*W[o][k]) + min_k(x[r][k]*W[o][k]) + b[o]
// x: (1024, 512) f32, W: (512, 512) f32, b: (512,), out: (1024, 512) f32.
//
// v7: fix v6's compiler-defeated register blocking. VGPR_Count=60 proved the
// compiler re-read W per row (DS-bound ~20us). Changes:
//  - j-OUTER / r-INNER: each w4 ds_read feeds all 4 rows immediately
//    (liveness = 1 float4) -> W DS reads cut 4x by construction
//  - K-split by 2: wave pairs own K-halves -> 4096 waves = 4 waves/SIMD,
//    1024 blocks = 4 blocks/CU (LDS 36 KB); tiny LDS max/min merge at end
//  - W staged global->LDS (global_load_lds w16, source pre-swizzled, linear
//    dest); in-loop b128 reads at phys granule j^(lane&7): 8 words/bank
//  - x: uniform global loads (no DS cycles)
// Budget/CU: DS ~6.8us, VALU ~6.8us, co-bound, overlapped across 16 waves.

#define O_TOTAL 512
#define K_TOTAL 512
#define OBLK 64
#define KHALF 256
#define KCH 32                   // K per phase (per half)
#define NPH (KHALF / KCH)        // 8 phases
#define RPW 4                    // rows per wave
#define NJ (KCH / 4)             // 8 granules per phase

__device__ __forceinline__ void stage16(const float* g, float* lds_base) {
#if __has_builtin(__builtin_amdgcn_global_load_lds)
  __builtin_amdgcn_global_load_lds(
      (__attribute__((address_space(1))) unsigned int*)g,
      (__attribute__((address_space(3))) unsigned int*)lds_base, 16, 0, 0);
#else
  *reinterpret_cast<float4*>(lds_base + (threadIdx.x & 63) * 4) =
      *reinterpret_cast<const float4*>(g);
#endif
}

__global__ __launch_bounds__(256, 4)
void mam_fc_kernel(const float* __restrict__ x, const float* __restrict__ W,
                   const float* __restrict__ bias, float* __restrict__ out) {
  // Wl[parity][half*2048 + row*32 + phys_granule*4], 2 x 16 KB
  __shared__ __align__(16) float Wl[2][2 * OBLK * KCH];
  __shared__ float red[2][RPW][64][2];   // 4 KB merge buffer

  const int t = threadIdx.x;
  const int lane = t & 63;
  const int wv = __builtin_amdgcn_readfirstlane(t >> 6);
  const int ob = blockIdx.x & 7;        // 8 out-blocks of 64
  const int rg = blockIdx.x >> 3;       // 128 row-groups of 8
  const int o0 = ob * OBLK;
  const int pair = wv >> 1;             // which 4-row group
  const int half = wv & 1;              // which K half
  const int rowBase = rg * 8 + pair * RPW;
  const int kBase = half * KHALF;

  // ---- staging plan: wave wv covers 1KB segments s = wv*4+i (16 segs = 16KB/phase)
  // seg s: half h = s>>3, rows (s&7)*8 + (lane>>3), phys granule lane&7.
  // Source pre-swizzled: logical granule g = (lane&7) ^ (row&7); LDS dest linear.
  const float* srcW[4];
  int dstOff[4];
#pragma unroll
  for (int i = 0; i < 4; ++i) {
    const int s = wv * 4 + i;
    const int h = s >> 3;
    const int so = s & 7;
    const int orow = so * 8 + (lane >> 3);
    const int g = (lane & 7) ^ (orow & 7);
    srcW[i] = W + (size_t)(o0 + orow) * K_TOTAL + h * KHALF + g * 4;
    dstOff[i] = h * (OBLK * KCH) + so * 256;   // floats, wave-uniform
  }

  float amax[RPW], amin[RPW];
#pragma unroll
  for (int r = 0; r < RPW; ++r) { amax[r] = -INFINITY; amin[r] = INFINITY; }

  // in-loop W read: row=lane (stride 128B), phys granule j^(lane&7); XOR fields disjoint
  const unsigned baseW = (unsigned)(lane * (KCH * 4) + (lane & 7) * 16);
  const float* xw = x + (size_t)rowBase * K_TOTAL + kBase;   // wave-uniform

  // prologue: stage phase 0 into parity 0
#pragma unroll
  for (int i = 0; i < 4; ++i) stage16(srcW[i], &Wl[0][dstOff[i]]);

#pragma unroll 1
  for (int p = 0; p < NPH; ++p) {
    __syncthreads();   // phase p staged (compiler drains vmcnt before barrier)

    if (p + 1 < NPH) {   // issue next phase staging; drained at NEXT barrier
#pragma unroll
      for (int i = 0; i < 4; ++i)
        stage16(srcW[i] + (p + 1) * KCH, &Wl[(p + 1) & 1][dstOff[i]]);
    }

    const char* wb = (const char*)&Wl[p & 1][half * (OBLK * KCH)];
    const float* xp = xw + p * KCH;
#pragma unroll
    for (int j = 0; j < NJ; ++j) {
      const float4 w4 = *reinterpret_cast<const float4*>(wb + (baseW ^ (unsigned)(j * 16)));
#pragma unroll
      for (int r = 0; r < RPW; ++r) {
        const float4 xv = *reinterpret_cast<const float4*>(xp + (size_t)r * K_TOTAL + j * 4);
        const float p0 = xv.x * w4.x;
        const float p1 = xv.y * w4.y;
        const float p2 = xv.z * w4.z;
        const float p3 = xv.w * w4.w;
        // 4-deep chains -> 2x v_max3 / 2x v_min3 per (j,r)
        amax[r] = fmaxf(fmaxf(fmaxf(fmaxf(amax[r], p0), p1), p2), p3);
        amin[r] = fminf(fminf(fminf(fminf(amin[r], p0), p1), p2), p3);
      }
    }
  }

  // ---- K-half merge: odd waves publish, even waves combine + store ----
  if (half) {
#pragma unroll
    for (int r = 0; r < RPW; ++r) {
      red[pair][r][lane][0] = amax[r];
      red[pair][r][lane][1] = amin[r];
    }
  }
  __syncthreads();
  if (!half) {
    const float bv = bias[o0 + lane];
#pragma unroll
    for (int r = 0; r < RPW; ++r) {
      const float m = fmaxf(amax[r], red[pair][r][lane][0]);
      const float n = fminf(amin[r], red[pair][r][lane][1]);
      out[(size_t)(rowBase + r) * O_TOTAL + o0 + lane] = m + n + bv;  // coalesced
    }
  }
}

extern "C" void kernel_launch(void* const* d_in, const int* in_sizes, int n_in,
                              void* d_out, int out_size, void* d_ws, size_t ws_size,
                              hipStream_t stream) {
  const float* x = (const float*)d_in[0];    // (1024, 512)
  const float* W = (const float*)d_in[1];    // (512, 512)
  const float* b = (const float*)d_in[2];    // (512,)
  float* out = (float*)d_out;                // (1024, 512)

  const int nrows = in_sizes[0] / K_TOTAL;               // 1024
  const int nblocks = (O_TOTAL / OBLK) * (nrows / 8);    // 8 * 128 = 1024
  mam_fc_kernel<<<dim3(nblocks), dim3(256), 0, stream>>>(x, W, b, out);
}